// Round 6
// baseline (446.345 us; speedup 1.0000x reference)
//
#include <hip/hip_runtime.h>

// ---------- types ----------
typedef __attribute__((ext_vector_type(8))) short short8;
typedef __attribute__((ext_vector_type(4))) float f32x4;
typedef __attribute__((ext_vector_type(4))) float float4v;
typedef __attribute__((ext_vector_type(4))) unsigned short us4;

__device__ __forceinline__ unsigned short f2bf(float f) {
  union { float f; unsigned int u; } c; c.f = f;
  unsigned int u = c.u;
  u += 0x7fffu + ((u >> 16) & 1u);
  return (unsigned short)(u >> 16);
}

// pack 2 fp32 -> 2 bf16 in one dword (lo = a, hi = b)
__device__ __forceinline__ unsigned int pkbf(float a, float b) {
  unsigned int r;
  asm("v_cvt_pk_bf16_f32 %0, %1, %2" : "=v"(r) : "v"(a), "v"(b));
  return r;
}

__device__ __forceinline__ void async16(const void* g, void* l) {
  __builtin_amdgcn_global_load_lds(
      (const __attribute__((address_space(1))) unsigned int*)g,
      (__attribute__((address_space(3))) unsigned int*)l, 16, 0, 0);
}

__device__ __forceinline__ f32x4 mfma16(short8 a, short8 b, f32x4 c) {
  return __builtin_amdgcn_mfma_f32_16x16x32_bf16(a, b, c, 0, 0, 0);
}

// ---------- fused fp32 -> bf16 cast, reordered for fused GEMMs ----------
__global__ void cast_all(const float* __restrict__ x,
                         const float* __restrict__ wqa, const float* __restrict__ wqb,
                         const float* __restrict__ wka, const float* __restrict__ wkb,
                         const float* __restrict__ wva, const float* __restrict__ wvb,
                         const float* __restrict__ wow,
                         unsigned short* __restrict__ out) {
  int c = blockIdx.x * 256 + threadIdx.x;
  const int stride = gridDim.x * 256;
  for (; c < 4718592; c += stride) {
    int i = c << 2;
    const float* src; int off;
    if (i < 8388608)       { src = x;   off = 0; }
    else if (i < 9437184)  { src = wqa; off = 8388608; }
    else if (i < 10485760) { src = wka; off = 9437184; }
    else if (i < 11534336) { src = wva; off = 10485760; }
    else if (i < 12582912) { src = wqb; off = 11534336; }
    else if (i < 13631488) { src = wkb; off = 12582912; }
    else if (i < 14680064) { src = wvb; off = 13631488; }
    else                   { src = wow; off = 14680064; }
    float4v v = *(const float4v*)(src + (i - off));
    us4 r;
    r[0] = f2bf(v[0]); r[1] = f2bf(v[1]); r[2] = f2bf(v[2]); r[3] = f2bf(v[3]);
    *(us4*)(out + i) = r;
  }
}

// ---------- GEMM body: C[M,N] = A[.,lda] * B[.,ldb]^T (bf16, K-contiguous) ----
// modes: 0 bf16 plain | 1 bf16 v-transposed + key-permuted | 2 fp32 +bias | 3 bf16 *qscale
__device__ __forceinline__ void gemm_body(
    const unsigned short* __restrict__ A, int lda,
    const unsigned short* __restrict__ B, int ldb,
    void* __restrict__ Cv, int ldc,
    const float* __restrict__ bias, float qscale, int K, int mode) {
  __shared__ __align__(16) unsigned short As[128 * 32];
  __shared__ __align__(16) unsigned short Bs[128 * 32];
  const int tid  = threadIdx.x;
  const int wave = tid >> 6, lane = tid & 63;
  const int lr = lane & 15, lg = lane >> 4;
  const int tile_m = blockIdx.y << 7;
  const int tile_n = blockIdx.x << 7;
  const int wm = (wave & 1) << 6;
  const int wn = (wave >> 1) << 6;

  f32x4 acc[4][4];
#pragma unroll
  for (int i = 0; i < 4; i++)
#pragma unroll
    for (int j = 0; j < 4; j++) acc[i][j] = (f32x4)0.0f;

  const int cg = ((tid & 3) ^ ((tid >> 3) & 3)) << 3;
  const unsigned short* Ag = A + (size_t)(tile_m + (tid >> 2)) * lda + cg;
  const unsigned short* Bg = B + (size_t)(tile_n + (tid >> 2)) * ldb + cg;
  const size_t rowskipA = (size_t)64 * lda;
  const size_t rowskipB = (size_t)64 * ldb;
  unsigned short* AsW = As + wave * 512;
  unsigned short* BsW = Bs + wave * 512;
  const int swa = ((lr >> 1) & 3);

  for (int k0 = 0; k0 < K; k0 += 32) {
    async16(Ag + k0,            AsW);
    async16(Ag + k0 + rowskipA, AsW + 2048);
    async16(Bg + k0,            BsW);
    async16(Bg + k0 + rowskipB, BsW + 2048);
    __syncthreads();
    short8 af[4], bf[4];
#pragma unroll
    for (int mt = 0; mt < 4; mt++)
      af[mt] = *(const short8*)&As[(wm + mt * 16 + lr) * 32 + ((lg ^ swa) << 3)];
#pragma unroll
    for (int nt = 0; nt < 4; nt++)
      bf[nt] = *(const short8*)&Bs[(wn + nt * 16 + lr) * 32 + ((lg ^ swa) << 3)];
#pragma unroll
    for (int mt = 0; mt < 4; mt++)
#pragma unroll
      for (int nt = 0; nt < 4; nt++)
        acc[mt][nt] = mfma16(af[mt], bf[nt], acc[mt][nt]);
    __syncthreads();
  }

#pragma unroll
  for (int mt = 0; mt < 4; mt++) {
#pragma unroll
    for (int nt = 0; nt < 4; nt++) {
#pragma unroll
      for (int r = 0; r < 4; r++) {
        int row = tile_m + wm + mt * 16 + lg * 4 + r;
        int col = tile_n + wn + nt * 16 + lr;
        float v = acc[mt][nt][r];
        if (mode == 0) {
          ((unsigned short*)Cv)[(size_t)row * ldc + col] = f2bf(v);
        } else if (mode == 3) {
          ((unsigned short*)Cv)[(size_t)row * ldc + col] = f2bf(v * qscale);
        } else if (mode == 1) {
          // v^T store with key permutation pi(key)=((key&15)<<2)|(key>>4) inside 64-blocks
          int tl = row & 2047;
          int key = tl & 63;
          int tp = (tl & ~63) | ((key & 15) << 2) | (key >> 4);
          ((unsigned short*)Cv)[((size_t)((row >> 11) << 11) + col) * 2048 + tp] = f2bf(v);
        } else {
          ((float*)Cv)[(size_t)row * ldc + col] = v + bias[col];
        }
      }
    }
  }
}

__global__ __launch_bounds__(256)
void gemm_k(const unsigned short* __restrict__ A, int lda,
            const unsigned short* __restrict__ B, int ldb,
            void* __restrict__ C, int ldc, const float* __restrict__ bias,
            int K, int mode) {
  gemm_body(A, lda, B, ldb, C, ldc, bias, 1.0f, K, mode);
}

// batched up-projection: z=0 -> Q (scaled), z=1 -> K, z=2 -> V^T permuted
__global__ __launch_bounds__(256)
void gemm_up(const unsigned short* __restrict__ cdown,
             const unsigned short* __restrict__ wup,
             unsigned short* __restrict__ qb,
             unsigned short* __restrict__ kb,
             unsigned short* __restrict__ vtb) {
  const int z = blockIdx.z;
  const unsigned short* A = cdown + z * 512;
  const unsigned short* B = wup + (size_t)z * 1048576;
  void* C; int mode; float qs = 1.0f;
  if (z == 0)      { C = qb;  mode = 3; qs = 0.12751744f; }  // (1/sqrt(128))*log2(e)
  else if (z == 1) { C = kb;  mode = 0; }
  else             { C = vtb; mode = 1; }
  gemm_body(A, 1536, B, 512, C, 2048, nullptr, qs, 512, mode);
}

// ---------- flash attention (unshifted softmax, log2 domain, 32 q-rows/wave) ----------
// q (pre-scaled), k: [4096][2048] bf16; vt: key-permuted per 64-block; o: [4096][2048]
// grid (16, 32): x = 128-row q-block, y = b*16+h.  Per wave: 2 strips of 16 q-rows.
__global__ __launch_bounds__(256)
void attn(const unsigned short* __restrict__ q,
          const unsigned short* __restrict__ k,
          const unsigned short* __restrict__ vt,
          unsigned short* __restrict__ o) {
  __shared__ __align__(16) unsigned short Ks[64 * 128];
  __shared__ __align__(16) unsigned short Vs[128 * 64];
  __shared__ __align__(16) unsigned short Ps[8][16 * 64];  // [wave*2+strip]

  const int tid  = threadIdx.x;
  const int wave = tid >> 6, lane = tid & 63;
  const int lr = lane & 15, lg = lane >> 4;
  const int bh = blockIdx.y;
  const int b = bh >> 4, h = bh & 15;
  const int q0 = blockIdx.x * 128;

  short8 qf[2][4];
#pragma unroll
  for (int s = 0; s < 2; s++) {
    const size_t qrow = (size_t)(b * 2048 + q0 + wave * 32 + s * 16 + lr);
#pragma unroll
    for (int kk = 0; kk < 4; kk++)
      qf[s][kk] = *(const short8*)(q + qrow * 2048 + h * 128 + kk * 32 + lg * 8);
  }

  f32x4 oacc[2][8];
  f32x4 lacc[2];
#pragma unroll
  for (int s = 0; s < 2; s++) {
    lacc[s] = (f32x4)0.0f;
#pragma unroll
    for (int n2 = 0; n2 < 8; n2++) oacc[s][n2] = (f32x4)0.0f;
  }

  short8 ones;
#pragma unroll
  for (int j = 0; j < 8; j++) ones[j] = (short)0x3F80;  // bf16 1.0

  const unsigned short* kg = k  + (size_t)(b * 2048 + (tid >> 4)) * 2048 + h * 128
                               + (((tid & 15) ^ (tid >> 4)) << 3);
  const unsigned short* vg = vt + (size_t)(bh * 128 + (tid >> 3)) * 2048
                               + (((tid & 7) ^ ((tid >> 3) & 7)) << 3);
  const int lr7 = lr & 7;

  for (int kt = 0; kt < 2048; kt += 64) {
#pragma unroll
    for (int i = 0; i < 4; i++) {
      async16(kg + (size_t)(kt + i * 16) * 2048, Ks + i * 2048 + wave * 512);
      async16(vg + kt + (size_t)(i * 32) * 2048, Vs + i * 2048 + wave * 512);
    }
    __syncthreads();

    // S = Q K^T for both strips, sharing each K fragment read
    f32x4 sv[2][4];
#pragma unroll
    for (int s = 0; s < 2; s++)
#pragma unroll
      for (int nt = 0; nt < 4; nt++) sv[s][nt] = (f32x4)0.0f;
#pragma unroll
    for (int nt = 0; nt < 4; nt++) {
#pragma unroll
      for (int kk = 0; kk < 4; kk++) {
        short8 kf = *(const short8*)&Ks[(nt * 16 + lr) * 128 + (((kk * 4 + lg) ^ lr) << 3)];
        sv[0][nt] = mfma16(qf[0][kk], kf, sv[0][nt]);
        sv[1][nt] = mfma16(qf[1][kk], kf, sv[1][nt]);
      }
    }

    // p = 2^s; packed bf16 write to Ps in permuted-key layout:
    // logical element (row, key'= lr*4+nt); physical chunk = (key'>>2) ^ ((row>>2)<<2)
#pragma unroll
    for (int s = 0; s < 2; s++) {
#pragma unroll
      for (int r = 0; r < 4; r++) {
        float p0 = exp2f(sv[s][0][r]);
        float p1 = exp2f(sv[s][1][r]);
        float p2 = exp2f(sv[s][2][r]);
        float p3 = exp2f(sv[s][3][r]);
        uint2 pk; pk.x = pkbf(p0, p1); pk.y = pkbf(p2, p3);
        int row = lg * 4 + r;
        *(uint2*)&Ps[wave * 2 + s][row * 64 + ((lr ^ (lg << 2)) << 2)] = pk;
      }
    }

    // O += P V ; l += P 1   (V fragments shared across strips)
#pragma unroll
    for (int kt2 = 0; kt2 < 2; kt2++) {
      short8 pf0 = *(const short8*)&Ps[wave * 2 + 0]
          [lr * 64 + (((kt2 * 8 + lg * 2) ^ ((lr >> 2) << 2)) << 2)];
      short8 pf1 = *(const short8*)&Ps[wave * 2 + 1]
          [lr * 64 + (((kt2 * 8 + lg * 2) ^ ((lr >> 2) << 2)) << 2)];
      lacc[0] = mfma16(pf0, ones, lacc[0]);
      lacc[1] = mfma16(pf1, ones, lacc[1]);
#pragma unroll
      for (int n2 = 0; n2 < 8; n2++) {
        short8 vf = *(const short8*)&Vs[(n2 * 16 + lr) * 64 + (((kt2 * 4 + lg) ^ lr7) << 3)];
        oacc[0][n2] = mfma16(pf0, vf, oacc[0][n2]);
        oacc[1][n2] = mfma16(pf1, vf, oacc[1][n2]);
      }
    }
    __syncthreads();
  }

  // epilogue: l lives in C-layout aligned with oacc rows — no shuffles needed
#pragma unroll
  for (int s = 0; s < 2; s++) {
    f32x4 inv;
#pragma unroll
    for (int r = 0; r < 4; r++) inv[r] = 1.0f / lacc[s][r];
#pragma unroll
    for (int n2 = 0; n2 < 8; n2++)
#pragma unroll
      for (int r = 0; r < 4; r++) {
        size_t row = (size_t)(b * 2048 + q0 + wave * 32 + s * 16 + lg * 4 + r);
        o[row * 2048 + h * 128 + n2 * 16 + lr] = f2bf(oacc[s][n2][r] * inv[r]);
      }
  }
}

// ---------- host ----------
extern "C" void kernel_launch(void* const* d_in, const int* in_sizes, int n_in,
                              void* d_out, int out_size, void* d_ws, size_t ws_size,
                              hipStream_t stream) {
  const float* x    = (const float*)d_in[0];
  const float* wq_a = (const float*)d_in[1];
  const float* wq_b = (const float*)d_in[2];
  const float* wk_a = (const float*)d_in[3];
  const float* wk_b = (const float*)d_in[4];
  const float* wv_a = (const float*)d_in[5];
  const float* wv_b = (const float*)d_in[6];
  const float* wo_w = (const float*)d_in[7];
  const float* wo_b = (const float*)d_in[8];
  float* out = (float*)d_out;

  unsigned short* ws = (unsigned short*)d_ws;
  unsigned short* xb    = ws;
  unsigned short* wdown = ws + 8388608;    // [1536][2048]
  unsigned short* wupb  = ws + 11534336;   // [3][2048][512]
  unsigned short* wow   = ws + 14680064;   // [2048][2048]
  unsigned short* cdown = ws + 18874368;   // [4096][1536]
  unsigned short* qb    = ws + 25165824;   // [4096][2048]
  unsigned short* kb    = ws + 33554432;
  unsigned short* vtb   = ws + 41943040;
  unsigned short* ao    = ws + 50331648;

  cast_all<<<dim3(2048), dim3(256), 0, stream>>>(x, wq_a, wq_b, wk_a, wk_b, wv_a, wv_b, wo_w, ws);

  // fused down-projection: [4096,2048] x [1536,2048]^T -> [4096,1536]
  gemm_k<<<dim3(12, 32), dim3(256), 0, stream>>>(xb, 2048, wdown, 2048, cdown, 1536, nullptr, 2048, 0);

  // batched up-projections (Q scaled, K plain, V transposed+permuted)
  gemm_up<<<dim3(16, 32, 3), dim3(256), 0, stream>>>(cdown, wupb, qb, kb, vtb);

  attn<<<dim3(16, 32), dim3(256), 0, stream>>>(qb, kb, vtb, ao);

  // output projection + bias -> fp32
  gemm_k<<<dim3(16, 32), dim3(256), 0, stream>>>(ao, 2048, wow, 2048, out, 2048, wo_b, 2048, 2);
}

// Round 7
// 414.989 us; speedup vs baseline: 1.0756x; 1.0756x over previous
//
#include <hip/hip_runtime.h>

// ---------- types ----------
typedef __attribute__((ext_vector_type(8))) short short8;
typedef __attribute__((ext_vector_type(4))) float f32x4;
typedef __attribute__((ext_vector_type(4))) float float4v;
typedef __attribute__((ext_vector_type(4))) unsigned short us4;

__device__ __forceinline__ unsigned short f2bf(float f) {
  union { float f; unsigned int u; } c; c.f = f;
  unsigned int u = c.u;
  u += 0x7fffu + ((u >> 16) & 1u);
  return (unsigned short)(u >> 16);
}

// pack 2 fp32 -> 2 bf16 in one dword (lo = a, hi = b)
__device__ __forceinline__ unsigned int pkbf(float a, float b) {
  unsigned int r;
  asm("v_cvt_pk_bf16_f32 %0, %1, %2" : "=v"(r) : "v"(a), "v"(b));
  return r;
}

__device__ __forceinline__ void async16(const void* g, void* l) {
  __builtin_amdgcn_global_load_lds(
      (const __attribute__((address_space(1))) unsigned int*)g,
      (__attribute__((address_space(3))) unsigned int*)l, 16, 0, 0);
}

__device__ __forceinline__ f32x4 mfma16(short8 a, short8 b, f32x4 c) {
  return __builtin_amdgcn_mfma_f32_16x16x32_bf16(a, b, c, 0, 0, 0);
}

// ---------- fused fp32 -> bf16 cast, reordered for fused GEMMs ----------
__global__ void cast_all(const float* __restrict__ x,
                         const float* __restrict__ wqa, const float* __restrict__ wqb,
                         const float* __restrict__ wka, const float* __restrict__ wkb,
                         const float* __restrict__ wva, const float* __restrict__ wvb,
                         const float* __restrict__ wow,
                         unsigned short* __restrict__ out) {
  int c = blockIdx.x * 256 + threadIdx.x;
  const int stride = gridDim.x * 256;
  for (; c < 4718592; c += stride) {
    int i = c << 2;
    const float* src; int off;
    if (i < 8388608)       { src = x;   off = 0; }
    else if (i < 9437184)  { src = wqa; off = 8388608; }
    else if (i < 10485760) { src = wka; off = 9437184; }
    else if (i < 11534336) { src = wva; off = 10485760; }
    else if (i < 12582912) { src = wqb; off = 11534336; }
    else if (i < 13631488) { src = wkb; off = 12582912; }
    else if (i < 14680064) { src = wvb; off = 13631488; }
    else                   { src = wow; off = 14680064; }
    float4v v = *(const float4v*)(src + (i - off));
    us4 r;
    r[0] = f2bf(v[0]); r[1] = f2bf(v[1]); r[2] = f2bf(v[2]); r[3] = f2bf(v[3]);
    *(us4*)(out + i) = r;
  }
}

// ---------- GEMM body: C[M,N] = A[.,lda] * B[.,ldb]^T (bf16, K-contiguous) ----
// modes: 0 bf16 plain | 1 bf16 v-transposed + key-permuted | 2 fp32 +bias | 3 bf16 *qscale
__device__ __forceinline__ void gemm_body(
    const unsigned short* __restrict__ A, int lda,
    const unsigned short* __restrict__ B, int ldb,
    void* __restrict__ Cv, int ldc,
    const float* __restrict__ bias, float qscale, int K, int mode) {
  __shared__ __align__(16) unsigned short As[128 * 32];
  __shared__ __align__(16) unsigned short Bs[128 * 32];
  const int tid  = threadIdx.x;
  const int wave = tid >> 6, lane = tid & 63;
  const int lr = lane & 15, lg = lane >> 4;
  const int tile_m = blockIdx.y << 7;
  const int tile_n = blockIdx.x << 7;
  const int wm = (wave & 1) << 6;
  const int wn = (wave >> 1) << 6;

  f32x4 acc[4][4];
#pragma unroll
  for (int i = 0; i < 4; i++)
#pragma unroll
    for (int j = 0; j < 4; j++) acc[i][j] = (f32x4)0.0f;

  const int cg = ((tid & 3) ^ ((tid >> 3) & 3)) << 3;
  const unsigned short* Ag = A + (size_t)(tile_m + (tid >> 2)) * lda + cg;
  const unsigned short* Bg = B + (size_t)(tile_n + (tid >> 2)) * ldb + cg;
  const size_t rowskipA = (size_t)64 * lda;
  const size_t rowskipB = (size_t)64 * ldb;
  unsigned short* AsW = As + wave * 512;
  unsigned short* BsW = Bs + wave * 512;
  const int swa = ((lr >> 1) & 3);

  for (int k0 = 0; k0 < K; k0 += 32) {
    async16(Ag + k0,            AsW);
    async16(Ag + k0 + rowskipA, AsW + 2048);
    async16(Bg + k0,            BsW);
    async16(Bg + k0 + rowskipB, BsW + 2048);
    __syncthreads();
    short8 af[4], bf[4];
#pragma unroll
    for (int mt = 0; mt < 4; mt++)
      af[mt] = *(const short8*)&As[(wm + mt * 16 + lr) * 32 + ((lg ^ swa) << 3)];
#pragma unroll
    for (int nt = 0; nt < 4; nt++)
      bf[nt] = *(const short8*)&Bs[(wn + nt * 16 + lr) * 32 + ((lg ^ swa) << 3)];
#pragma unroll
    for (int mt = 0; mt < 4; mt++)
#pragma unroll
      for (int nt = 0; nt < 4; nt++)
        acc[mt][nt] = mfma16(af[mt], bf[nt], acc[mt][nt]);
    __syncthreads();
  }

#pragma unroll
  for (int mt = 0; mt < 4; mt++) {
#pragma unroll
    for (int nt = 0; nt < 4; nt++) {
#pragma unroll
      for (int r = 0; r < 4; r++) {
        int row = tile_m + wm + mt * 16 + lg * 4 + r;
        int col = tile_n + wn + nt * 16 + lr;
        float v = acc[mt][nt][r];
        if (mode == 0) {
          ((unsigned short*)Cv)[(size_t)row * ldc + col] = f2bf(v);
        } else if (mode == 3) {
          ((unsigned short*)Cv)[(size_t)row * ldc + col] = f2bf(v * qscale);
        } else if (mode == 1) {
          // v^T store with key permutation pi(key)=((key&15)<<2)|(key>>4) inside 64-blocks
          int tl = row & 2047;
          int key = tl & 63;
          int tp = (tl & ~63) | ((key & 15) << 2) | (key >> 4);
          ((unsigned short*)Cv)[((size_t)((row >> 11) << 11) + col) * 2048 + tp] = f2bf(v);
        } else {
          ((float*)Cv)[(size_t)row * ldc + col] = v + bias[col];
        }
      }
    }
  }
}

__global__ __launch_bounds__(256)
void gemm_k(const unsigned short* __restrict__ A, int lda,
            const unsigned short* __restrict__ B, int ldb,
            void* __restrict__ C, int ldc, const float* __restrict__ bias,
            int K, int mode) {
  gemm_body(A, lda, B, ldb, C, ldc, bias, 1.0f, K, mode);
}

// batched up-projection: z=0 -> Q (scaled), z=1 -> K, z=2 -> V^T permuted
__global__ __launch_bounds__(256)
void gemm_up(const unsigned short* __restrict__ cdown,
             const unsigned short* __restrict__ wup,
             unsigned short* __restrict__ qb,
             unsigned short* __restrict__ kb,
             unsigned short* __restrict__ vtb) {
  const int z = blockIdx.z;
  const unsigned short* A = cdown + z * 512;
  const unsigned short* B = wup + (size_t)z * 1048576;
  void* C; int mode; float qs = 1.0f;
  if (z == 0)      { C = qb;  mode = 3; qs = 0.12751744f; }  // (1/sqrt(128))*log2(e)
  else if (z == 1) { C = kb;  mode = 0; }
  else             { C = vtb; mode = 1; }
  gemm_body(A, 1536, B, 512, C, 2048, nullptr, qs, 512, mode);
}

// ---------- flash attention (unshifted softmax, log2 domain, 16 q-rows/wave) ----------
// Round-5 occupancy structure + round-6 VALU wins (pkbf P-writes, MFMA-ones l,
// permuted-key V^T).  grid (32, 32); LDS 40KB; VGPR ~90.
__global__ __launch_bounds__(256)
void attn(const unsigned short* __restrict__ q,
          const unsigned short* __restrict__ k,
          const unsigned short* __restrict__ vt,
          unsigned short* __restrict__ o) {
  __shared__ __align__(16) unsigned short Ks[64 * 128];
  __shared__ __align__(16) unsigned short Vs[128 * 64];
  __shared__ __align__(16) unsigned short Ps[4][16 * 64];

  const int tid  = threadIdx.x;
  const int wave = tid >> 6, lane = tid & 63;
  const int lr = lane & 15, lg = lane >> 4;
  const int bh = blockIdx.y;
  const int b = bh >> 4, h = bh & 15;
  const int q0 = blockIdx.x * 64;

  const size_t qrow = (size_t)(b * 2048 + q0 + wave * 16 + lr);
  short8 qf[4];
#pragma unroll
  for (int kk = 0; kk < 4; kk++)
    qf[kk] = *(const short8*)(q + qrow * 2048 + h * 128 + kk * 32 + lg * 8);

  f32x4 oacc[8];
  f32x4 lacc = (f32x4)0.0f;
#pragma unroll
  for (int n2 = 0; n2 < 8; n2++) oacc[n2] = (f32x4)0.0f;

  short8 ones;
#pragma unroll
  for (int j = 0; j < 8; j++) ones[j] = (short)0x3F80;  // bf16 1.0

  const unsigned short* kg = k  + (size_t)(b * 2048 + (tid >> 4)) * 2048 + h * 128
                               + (((tid & 15) ^ (tid >> 4)) << 3);
  const unsigned short* vg = vt + (size_t)(bh * 128 + (tid >> 3)) * 2048
                               + (((tid & 7) ^ ((tid >> 3) & 7)) << 3);
  const int lr7 = lr & 7;

  for (int kt = 0; kt < 2048; kt += 64) {
#pragma unroll
    for (int i = 0; i < 4; i++) {
      async16(kg + (size_t)(kt + i * 16) * 2048, Ks + i * 2048 + wave * 512);
      async16(vg + kt + (size_t)(i * 32) * 2048, Vs + i * 2048 + wave * 512);
    }
    __syncthreads();

    // S = Q K^T
    f32x4 sv[4];
#pragma unroll
    for (int nt = 0; nt < 4; nt++) sv[nt] = (f32x4)0.0f;
#pragma unroll
    for (int nt = 0; nt < 4; nt++) {
#pragma unroll
      for (int kk = 0; kk < 4; kk++) {
        short8 kf = *(const short8*)&Ks[(nt * 16 + lr) * 128 + (((kk * 4 + lg) ^ lr) << 3)];
        sv[nt] = mfma16(qf[kk], kf, sv[nt]);
      }
    }

    // p = 2^s; packed bf16 write to Ps in permuted-key layout
    // logical (row, key'=lr*4+nt); physical chunk-of-4 = lr ^ (lg<<2)
#pragma unroll
    for (int r = 0; r < 4; r++) {
      float p0 = exp2f(sv[0][r]);
      float p1 = exp2f(sv[1][r]);
      float p2 = exp2f(sv[2][r]);
      float p3 = exp2f(sv[3][r]);
      uint2 pk; pk.x = pkbf(p0, p1); pk.y = pkbf(p2, p3);
      int row = lg * 4 + r;
      *(uint2*)&Ps[wave][row * 64 + ((lr ^ (lg << 2)) << 2)] = pk;
    }

    // O += P V ; l += P 1
#pragma unroll
    for (int kt2 = 0; kt2 < 2; kt2++) {
      short8 pf = *(const short8*)&Ps[wave]
          [lr * 64 + (((kt2 * 8 + lg * 2) ^ ((lr >> 2) << 2)) << 2)];
      lacc = mfma16(pf, ones, lacc);
#pragma unroll
      for (int n2 = 0; n2 < 8; n2++) {
        short8 vf = *(const short8*)&Vs[(n2 * 16 + lr) * 64 + (((kt2 * 4 + lg) ^ lr7) << 3)];
        oacc[n2] = mfma16(pf, vf, oacc[n2]);
      }
    }
    __syncthreads();
  }

  // epilogue: l in C-layout aligned with oacc rows — no shuffles
  f32x4 inv;
#pragma unroll
  for (int r = 0; r < 4; r++) inv[r] = 1.0f / lacc[r];
#pragma unroll
  for (int n2 = 0; n2 < 8; n2++)
#pragma unroll
    for (int r = 0; r < 4; r++) {
      size_t row = (size_t)(b * 2048 + q0 + wave * 16 + lg * 4 + r);
      o[row * 2048 + h * 128 + n2 * 16 + lr] = f2bf(oacc[n2][r] * inv[r]);
    }
}

// ---------- host ----------
extern "C" void kernel_launch(void* const* d_in, const int* in_sizes, int n_in,
                              void* d_out, int out_size, void* d_ws, size_t ws_size,
                              hipStream_t stream) {
  const float* x    = (const float*)d_in[0];
  const float* wq_a = (const float*)d_in[1];
  const float* wq_b = (const float*)d_in[2];
  const float* wk_a = (const float*)d_in[3];
  const float* wk_b = (const float*)d_in[4];
  const float* wv_a = (const float*)d_in[5];
  const float* wv_b = (const float*)d_in[6];
  const float* wo_w = (const float*)d_in[7];
  const float* wo_b = (const float*)d_in[8];
  float* out = (float*)d_out;

  unsigned short* ws = (unsigned short*)d_ws;
  unsigned short* xb    = ws;
  unsigned short* wdown = ws + 8388608;    // [1536][2048]
  unsigned short* wupb  = ws + 11534336;   // [3][2048][512]
  unsigned short* wow   = ws + 14680064;   // [2048][2048]
  unsigned short* cdown = ws + 18874368;   // [4096][1536]
  unsigned short* qb    = ws + 25165824;   // [4096][2048]
  unsigned short* kb    = ws + 33554432;
  unsigned short* vtb   = ws + 41943040;
  unsigned short* ao    = ws + 50331648;

  cast_all<<<dim3(2048), dim3(256), 0, stream>>>(x, wq_a, wq_b, wk_a, wk_b, wv_a, wv_b, wo_w, ws);

  // fused down-projection: [4096,2048] x [1536,2048]^T -> [4096,1536]
  gemm_k<<<dim3(12, 32), dim3(256), 0, stream>>>(xb, 2048, wdown, 2048, cdown, 1536, nullptr, 2048, 0);

  // batched up-projections (Q scaled, K plain, V transposed+permuted)
  gemm_up<<<dim3(16, 32, 3), dim3(256), 0, stream>>>(cdown, wupb, qb, kb, vtb);

  attn<<<dim3(32, 32), dim3(256), 0, stream>>>(qb, kb, vtb, ao);

  // output projection + bias -> fp32
  gemm_k<<<dim3(16, 32), dim3(256), 0, stream>>>(ao, 2048, wow, 2048, out, 2048, wo_b, 2048, 2);
}

// Round 9
// 368.217 us; speedup vs baseline: 1.2122x; 1.1270x over previous
//
#include <hip/hip_runtime.h>

// ---------- types ----------
typedef __attribute__((ext_vector_type(8))) short short8;
typedef __attribute__((ext_vector_type(4))) float f32x4;
typedef __attribute__((ext_vector_type(4))) float float4v;
typedef __attribute__((ext_vector_type(4))) unsigned short us4;

__device__ __forceinline__ unsigned short f2bf(float f) {
  union { float f; unsigned int u; } c; c.f = f;
  unsigned int u = c.u;
  u += 0x7fffu + ((u >> 16) & 1u);
  return (unsigned short)(u >> 16);
}

__device__ __forceinline__ unsigned int pkbf(float a, float b) {
  unsigned int r;
  asm("v_cvt_pk_bf16_f32 %0, %1, %2" : "=v"(r) : "v"(a), "v"(b));
  return r;
}

// 2^x via compiler-known TRANS op (hazard nops handled by backend).
// Raw inline-asm v_exp_f32 is UNSAFE: TRANS->consumer wait states are invisible
// to the hazard recognizer inside an asm string (round-8 failure).
__device__ __forceinline__ float exp2r(float x) {
#if __has_builtin(__builtin_amdgcn_exp2f)
  return __builtin_amdgcn_exp2f(x);
#else
  return exp2f(x);
#endif
}

__device__ __forceinline__ void async16(const void* g, void* l) {
  __builtin_amdgcn_global_load_lds(
      (const __attribute__((address_space(1))) unsigned int*)g,
      (__attribute__((address_space(3))) unsigned int*)l, 16, 0, 0);
}

__device__ __forceinline__ f32x4 mfma16(short8 a, short8 b, f32x4 c) {
  return __builtin_amdgcn_mfma_f32_16x16x32_bf16(a, b, c, 0, 0, 0);
}

// ---------- fused fp32 -> bf16 cast, reordered for fused GEMMs ----------
__global__ void cast_all(const float* __restrict__ x,
                         const float* __restrict__ wqa, const float* __restrict__ wqb,
                         const float* __restrict__ wka, const float* __restrict__ wkb,
                         const float* __restrict__ wva, const float* __restrict__ wvb,
                         const float* __restrict__ wow,
                         unsigned short* __restrict__ out) {
  int c = blockIdx.x * 256 + threadIdx.x;
  const int stride = gridDim.x * 256;
  for (; c < 4718592; c += stride) {
    int i = c << 2;
    const float* src; int off;
    if (i < 8388608)       { src = x;   off = 0; }
    else if (i < 9437184)  { src = wqa; off = 8388608; }
    else if (i < 10485760) { src = wka; off = 9437184; }
    else if (i < 11534336) { src = wva; off = 10485760; }
    else if (i < 12582912) { src = wqb; off = 11534336; }
    else if (i < 13631488) { src = wkb; off = 12582912; }
    else if (i < 14680064) { src = wvb; off = 13631488; }
    else                   { src = wow; off = 14680064; }
    float4v v = *(const float4v*)(src + (i - off));
    us4 r;
    r[0] = f2bf(v[0]); r[1] = f2bf(v[1]); r[2] = f2bf(v[2]); r[3] = f2bf(v[3]);
    *(us4*)(out + i) = r;
  }
}

// ---------- GEMM body: C[M,N] = A[.,lda] * B[.,ldb]^T (bf16, K-contiguous) ----
// Tile 128 x BN (BN = 128 or 64).  modes: 0 bf16 | 1 bf16 v^T+key-perm | 2 fp32+bias | 3 bf16*qscale
template <int BN>
__device__ __forceinline__ void gemm_body(
    const unsigned short* __restrict__ A, int lda,
    const unsigned short* __restrict__ B, int ldb,
    void* __restrict__ Cv, int ldc,
    const float* __restrict__ bias, float qscale, int K, int mode) {
  constexpr int NT = BN / 32;           // nt sub-tiles per wave
  __shared__ __align__(16) unsigned short As[128 * 32];
  __shared__ __align__(16) unsigned short Bs[BN * 32];
  const int tid  = threadIdx.x;
  const int wave = tid >> 6, lane = tid & 63;
  const int lr = lane & 15, lg = lane >> 4;
  const int tile_m = blockIdx.y << 7;
  const int tile_n = blockIdx.x * BN;
  const int wm = (wave & 1) << 6;
  const int wn = (wave >> 1) * (BN / 2);

  f32x4 acc[4][NT];
#pragma unroll
  for (int i = 0; i < 4; i++)
#pragma unroll
    for (int j = 0; j < NT; j++) acc[i][j] = (f32x4)0.0f;

  const int cg = ((tid & 3) ^ ((tid >> 3) & 3)) << 3;
  const unsigned short* Ag = A + (size_t)(tile_m + (tid >> 2)) * lda + cg;
  const unsigned short* Bg = B + (size_t)(tile_n + (tid >> 2)) * ldb + cg;
  const size_t rowskipA = (size_t)64 * lda;
  const size_t rowskipB = (size_t)64 * ldb;
  unsigned short* AsW = As + wave * 512;
  unsigned short* BsW = Bs + wave * 512;
  const int swa = ((lr >> 1) & 3);

  for (int k0 = 0; k0 < K; k0 += 32) {
    async16(Ag + k0,            AsW);
    async16(Ag + k0 + rowskipA, AsW + 2048);
#pragma unroll
    for (int i = 0; i < BN / 64; i++)
      async16(Bg + k0 + i * rowskipB, BsW + i * 2048);
    __syncthreads();
    short8 af[4], bf[NT];
#pragma unroll
    for (int mt = 0; mt < 4; mt++)
      af[mt] = *(const short8*)&As[(wm + mt * 16 + lr) * 32 + ((lg ^ swa) << 3)];
#pragma unroll
    for (int nt = 0; nt < NT; nt++)
      bf[nt] = *(const short8*)&Bs[(wn + nt * 16 + lr) * 32 + ((lg ^ swa) << 3)];
#pragma unroll
    for (int mt = 0; mt < 4; mt++)
#pragma unroll
      for (int nt = 0; nt < NT; nt++)
        acc[mt][nt] = mfma16(af[mt], bf[nt], acc[mt][nt]);
    __syncthreads();
  }

#pragma unroll
  for (int mt = 0; mt < 4; mt++) {
#pragma unroll
    for (int nt = 0; nt < NT; nt++) {
#pragma unroll
      for (int r = 0; r < 4; r++) {
        int row = tile_m + wm + mt * 16 + lg * 4 + r;
        int col = tile_n + wn + nt * 16 + lr;
        float v = acc[mt][nt][r];
        if (mode == 0) {
          ((unsigned short*)Cv)[(size_t)row * ldc + col] = f2bf(v);
        } else if (mode == 3) {
          ((unsigned short*)Cv)[(size_t)row * ldc + col] = f2bf(v * qscale);
        } else if (mode == 1) {
          int tl = row & 2047;
          int key = tl & 63;
          int tp = (tl & ~63) | ((key & 15) << 2) | (key >> 4);
          ((unsigned short*)Cv)[((size_t)((row >> 11) << 11) + col) * 2048 + tp] = f2bf(v);
        } else {
          ((float*)Cv)[(size_t)row * ldc + col] = v + bias[col];
        }
      }
    }
  }
}

__global__ __launch_bounds__(256)
void gemm_k128(const unsigned short* __restrict__ A, int lda,
               const unsigned short* __restrict__ B, int ldb,
               void* __restrict__ C, int ldc, const float* __restrict__ bias,
               int K, int mode) {
  gemm_body<128>(A, lda, B, ldb, C, ldc, bias, 1.0f, K, mode);
}

__global__ __launch_bounds__(256)
void gemm_k64(const unsigned short* __restrict__ A, int lda,
              const unsigned short* __restrict__ B, int ldb,
              void* __restrict__ C, int ldc, const float* __restrict__ bias,
              int K, int mode) {
  gemm_body<64>(A, lda, B, ldb, C, ldc, bias, 1.0f, K, mode);
}

// batched up-projection: z=0 -> Q (scaled), z=1 -> K, z=2 -> V^T permuted
__global__ __launch_bounds__(256)
void gemm_up(const unsigned short* __restrict__ cdown,
             const unsigned short* __restrict__ wup,
             unsigned short* __restrict__ qb,
             unsigned short* __restrict__ kb,
             unsigned short* __restrict__ vtb) {
  const int z = blockIdx.z;
  const unsigned short* A = cdown + z * 512;
  const unsigned short* B = wup + (size_t)z * 1048576;
  void* C; int mode; float qs = 1.0f;
  if (z == 0)      { C = qb;  mode = 3; qs = 0.12751744f; }  // (1/sqrt(128))*log2(e)
  else if (z == 1) { C = kb;  mode = 0; }
  else             { C = vtb; mode = 1; }
  gemm_body<128>(A, 1536, B, 512, C, 2048, nullptr, qs, 512, mode);
}

// ---------- flash attention (unshifted softmax, log2 domain) ----------
// 512 threads / 8 waves / 128 q-rows per block; 16 q-rows per wave.
// K/V staged once per block for all 8 waves -> staging per q-row halved.
__global__ __launch_bounds__(512)
void attn(const unsigned short* __restrict__ q,
          const unsigned short* __restrict__ k,
          const unsigned short* __restrict__ vt,
          unsigned short* __restrict__ o) {
  __shared__ __align__(16) unsigned short Ks[64 * 128];
  __shared__ __align__(16) unsigned short Vs[128 * 64];
  __shared__ __align__(16) unsigned short Ps[8][16 * 64];

  const int tid  = threadIdx.x;
  const int wave = tid >> 6, lane = tid & 63;
  const int lr = lane & 15, lg = lane >> 4;
  const int bh = blockIdx.y;
  const int b = bh >> 4, h = bh & 15;
  const int q0 = blockIdx.x * 128;

  const size_t qrow = (size_t)(b * 2048 + q0 + wave * 16 + lr);
  short8 qf[4];
#pragma unroll
  for (int kk = 0; kk < 4; kk++)
    qf[kk] = *(const short8*)(q + qrow * 2048 + h * 128 + kk * 32 + lg * 8);

  f32x4 oacc[8];
  f32x4 lacc = (f32x4)0.0f;
#pragma unroll
  for (int n2 = 0; n2 < 8; n2++) oacc[n2] = (f32x4)0.0f;

  short8 ones;
#pragma unroll
  for (int j = 0; j < 8; j++) ones[j] = (short)0x3F80;  // bf16 1.0

  const unsigned short* kg = k  + (size_t)(b * 2048 + (tid >> 4)) * 2048 + h * 128
                               + ((((tid & 15) ^ (tid >> 4)) & 15) << 3);
  const unsigned short* vg = vt + (size_t)(bh * 128 + (tid >> 3)) * 2048
                               + (((tid & 7) ^ ((tid >> 3) & 7)) << 3);
  const int lr7 = lr & 7;

  for (int kt = 0; kt < 2048; kt += 64) {
#pragma unroll
    for (int i = 0; i < 2; i++) {
      async16(kg + (size_t)(kt + i * 32) * 2048, Ks + i * 4096 + wave * 512);
      async16(vg + kt + (size_t)(i * 64) * 2048, Vs + i * 4096 + wave * 512);
    }
    __syncthreads();

    // S = Q K^T
    f32x4 sv[4];
#pragma unroll
    for (int nt = 0; nt < 4; nt++) sv[nt] = (f32x4)0.0f;
#pragma unroll
    for (int nt = 0; nt < 4; nt++) {
#pragma unroll
      for (int kk = 0; kk < 4; kk++) {
        short8 kf = *(const short8*)&Ks[(nt * 16 + lr) * 128 + (((kk * 4 + lg) ^ lr) << 3)];
        sv[nt] = mfma16(qf[kk], kf, sv[nt]);
      }
    }

    // p = 2^s; packed bf16 write to Ps in permuted-key layout
#pragma unroll
    for (int r = 0; r < 4; r++) {
      float p0 = exp2r(sv[0][r]);
      float p1 = exp2r(sv[1][r]);
      float p2 = exp2r(sv[2][r]);
      float p3 = exp2r(sv[3][r]);
      uint2 pk; pk.x = pkbf(p0, p1); pk.y = pkbf(p2, p3);
      int row = lg * 4 + r;
      *(uint2*)&Ps[wave][row * 64 + ((lr ^ (lg << 2)) << 2)] = pk;
    }

    // O += P V ; l += P 1
#pragma unroll
    for (int kt2 = 0; kt2 < 2; kt2++) {
      short8 pf = *(const short8*)&Ps[wave]
          [lr * 64 + (((kt2 * 8 + lg * 2) ^ ((lr >> 2) << 2)) << 2)];
      lacc = mfma16(pf, ones, lacc);
#pragma unroll
      for (int n2 = 0; n2 < 8; n2++) {
        short8 vf = *(const short8*)&Vs[(n2 * 16 + lr) * 64 + (((kt2 * 4 + lg) ^ lr7) << 3)];
        oacc[n2] = mfma16(pf, vf, oacc[n2]);
      }
    }
    __syncthreads();
  }

  // epilogue: l in C-layout aligned with oacc rows
  f32x4 inv;
#pragma unroll
  for (int r = 0; r < 4; r++) inv[r] = 1.0f / lacc[r];
#pragma unroll
  for (int n2 = 0; n2 < 8; n2++)
#pragma unroll
    for (int r = 0; r < 4; r++) {
      size_t row = (size_t)(b * 2048 + q0 + wave * 16 + lg * 4 + r);
      o[row * 2048 + h * 128 + n2 * 16 + lr] = f2bf(oacc[n2][r] * inv[r]);
    }
}

// ---------- host ----------
extern "C" void kernel_launch(void* const* d_in, const int* in_sizes, int n_in,
                              void* d_out, int out_size, void* d_ws, size_t ws_size,
                              hipStream_t stream) {
  const float* x    = (const float*)d_in[0];
  const float* wq_a = (const float*)d_in[1];
  const float* wq_b = (const float*)d_in[2];
  const float* wk_a = (const float*)d_in[3];
  const float* wk_b = (const float*)d_in[4];
  const float* wv_a = (const float*)d_in[5];
  const float* wv_b = (const float*)d_in[6];
  const float* wo_w = (const float*)d_in[7];
  const float* wo_b = (const float*)d_in[8];
  float* out = (float*)d_out;

  unsigned short* ws = (unsigned short*)d_ws;
  unsigned short* xb    = ws;
  unsigned short* wdown = ws + 8388608;    // [1536][2048]
  unsigned short* wupb  = ws + 11534336;   // [3][2048][512]
  unsigned short* wow   = ws + 14680064;   // [2048][2048]
  unsigned short* cdown = ws + 18874368;   // [4096][1536]
  unsigned short* qb    = ws + 25165824;   // [4096][2048]
  unsigned short* kb    = ws + 33554432;
  unsigned short* vtb   = ws + 41943040;
  unsigned short* ao    = ws + 50331648;

  cast_all<<<dim3(2048), dim3(256), 0, stream>>>(x, wq_a, wq_b, wk_a, wk_b, wv_a, wv_b, wo_w, ws);

  // fused down-projection: [4096,2048] x [1536,2048]^T -> [4096,1536], 64-col tiles
  gemm_k64<<<dim3(24, 32), dim3(256), 0, stream>>>(xb, 2048, wdown, 2048, cdown, 1536, nullptr, 2048, 0);

  // batched up-projections (Q scaled, K plain, V transposed+permuted)
  gemm_up<<<dim3(16, 32, 3), dim3(256), 0, stream>>>(cdown, wupb, qb, kb, vtb);

  attn<<<dim3(16, 32), dim3(512), 0, stream>>>(qb, kb, vtb, ao);

  // output projection + bias -> fp32
  gemm_k128<<<dim3(16, 32), dim3(256), 0, stream>>>(ao, 2048, wow, 2048, out, 2048, wo_b, 2048, 2);
}

// Round 10
// 345.023 us; speedup vs baseline: 1.2937x; 1.0672x over previous
//
#include <hip/hip_runtime.h>

// ---------- types ----------
typedef __attribute__((ext_vector_type(8))) short short8;
typedef __attribute__((ext_vector_type(4))) float f32x4;
typedef __attribute__((ext_vector_type(4))) float float4v;
typedef __attribute__((ext_vector_type(4))) unsigned short us4;

__device__ __forceinline__ unsigned short f2bf(float f) {
  union { float f; unsigned int u; } c; c.f = f;
  unsigned int u = c.u;
  u += 0x7fffu + ((u >> 16) & 1u);
  return (unsigned short)(u >> 16);
}

__device__ __forceinline__ unsigned int pkbf(float a, float b) {
  unsigned int r;
  asm("v_cvt_pk_bf16_f32 %0, %1, %2" : "=v"(r) : "v"(a), "v"(b));
  return r;
}

// 2^x via compiler-known TRANS op (hazard nops handled by backend).
// Raw inline-asm v_exp_f32 is UNSAFE (round-8 failure: TRANS wait-states
// invisible to the hazard recognizer inside asm strings).
__device__ __forceinline__ float exp2r(float x) {
#if __has_builtin(__builtin_amdgcn_exp2f)
  return __builtin_amdgcn_exp2f(x);
#else
  return exp2f(x);
#endif
}

__device__ __forceinline__ void async16(const void* g, void* l) {
  __builtin_amdgcn_global_load_lds(
      (const __attribute__((address_space(1))) unsigned int*)g,
      (__attribute__((address_space(3))) unsigned int*)l, 16, 0, 0);
}

__device__ __forceinline__ f32x4 mfma16(short8 a, short8 b, f32x4 c) {
  return __builtin_amdgcn_mfma_f32_16x16x32_bf16(a, b, c, 0, 0, 0);
}

// ---------- fused fp32 -> bf16 cast, reordered for fused GEMMs ----------
__global__ void cast_all(const float* __restrict__ x,
                         const float* __restrict__ wqa, const float* __restrict__ wqb,
                         const float* __restrict__ wka, const float* __restrict__ wkb,
                         const float* __restrict__ wva, const float* __restrict__ wvb,
                         const float* __restrict__ wow,
                         unsigned short* __restrict__ out) {
  int c = blockIdx.x * 256 + threadIdx.x;
  const int stride = gridDim.x * 256;
  for (; c < 4718592; c += stride) {
    int i = c << 2;
    const float* src; int off;
    if (i < 8388608)       { src = x;   off = 0; }
    else if (i < 9437184)  { src = wqa; off = 8388608; }
    else if (i < 10485760) { src = wka; off = 9437184; }
    else if (i < 11534336) { src = wva; off = 10485760; }
    else if (i < 12582912) { src = wqb; off = 11534336; }
    else if (i < 13631488) { src = wkb; off = 12582912; }
    else if (i < 14680064) { src = wvb; off = 13631488; }
    else                   { src = wow; off = 14680064; }
    float4v v = *(const float4v*)(src + (i - off));
    us4 r;
    r[0] = f2bf(v[0]); r[1] = f2bf(v[1]); r[2] = f2bf(v[2]); r[3] = f2bf(v[3]);
    *(us4*)(out + i) = r;
  }
}

// ---------- GEMM body: C[M,N] = A[.,lda] * B[.,ldb]^T (bf16, K-contiguous) ----
// BK=64 K-loop: one barrier pair per 64-K (half the barriers of BK=32).
// LDS rows of 64 elems = 8 chunks of 16B, chunk swizzled by (row&7) -> the
// read pattern (kk*4+lg)^(lr&7) matches attn's Vs reads (measured 0 conflicts).
// modes: 0 bf16 | 1 bf16 v^T+key-perm | 2 fp32+bias | 3 bf16*qscale
template <int BN>
__device__ __forceinline__ void gemm_body(
    const unsigned short* __restrict__ A, int lda,
    const unsigned short* __restrict__ B, int ldb,
    void* __restrict__ Cv, int ldc,
    const float* __restrict__ bias, float qscale, int K, int mode) {
  constexpr int NT = BN / 32;
  __shared__ __align__(16) unsigned short As[128 * 64];
  __shared__ __align__(16) unsigned short Bs[BN * 64];
  const int tid  = threadIdx.x;
  const int wave = tid >> 6, lane = tid & 63;
  const int lr = lane & 15, lg = lane >> 4;
  const int lr7 = lr & 7;
  const int tile_m = blockIdx.y << 7;
  const int tile_n = blockIdx.x * BN;
  const int wm = (wave & 1) << 6;
  const int wn = (wave >> 1) * (BN / 2);

  f32x4 acc[4][NT];
#pragma unroll
  for (int i = 0; i < 4; i++)
#pragma unroll
    for (int j = 0; j < NT; j++) acc[i][j] = (f32x4)0.0f;

  // staging: thread covers row (tid>>3)+32i, chunk (tid&7)^((tid>>3)&7)
  // (row&7 is invariant across i since 32i ≡ 0 mod 8)
  const int srow = tid >> 3;
  const int cg = ((tid & 7) ^ (srow & 7)) << 3;
  const unsigned short* Ag = A + (size_t)(tile_m + srow) * lda + cg;
  const unsigned short* Bg = B + (size_t)(tile_n + srow) * ldb + cg;
  const size_t rowskipA = (size_t)32 * lda;
  const size_t rowskipB = (size_t)32 * ldb;
  unsigned short* AsW = As + wave * 512;   // wave covers rows w*8..w*8+7 per issue
  unsigned short* BsW = Bs + wave * 512;

  for (int k0 = 0; k0 < K; k0 += 64) {
#pragma unroll
    for (int i = 0; i < 4; i++)
      async16(Ag + k0 + i * rowskipA, AsW + i * 2048);
#pragma unroll
    for (int i = 0; i < BN / 32; i++)
      async16(Bg + k0 + i * rowskipB, BsW + i * 2048);
    __syncthreads();
#pragma unroll
    for (int kk = 0; kk < 2; kk++) {
      short8 af[4], bf[NT];
#pragma unroll
      for (int mt = 0; mt < 4; mt++)
        af[mt] = *(const short8*)&As[(wm + mt * 16 + lr) * 64 + (((kk * 4 + lg) ^ lr7) << 3)];
#pragma unroll
      for (int nt = 0; nt < NT; nt++)
        bf[nt] = *(const short8*)&Bs[(wn + nt * 16 + lr) * 64 + (((kk * 4 + lg) ^ lr7) << 3)];
#pragma unroll
      for (int mt = 0; mt < 4; mt++)
#pragma unroll
        for (int nt = 0; nt < NT; nt++)
          acc[mt][nt] = mfma16(af[mt], bf[nt], acc[mt][nt]);
    }
    __syncthreads();
  }

#pragma unroll
  for (int mt = 0; mt < 4; mt++) {
#pragma unroll
    for (int nt = 0; nt < NT; nt++) {
#pragma unroll
      for (int r = 0; r < 4; r++) {
        int row = tile_m + wm + mt * 16 + lg * 4 + r;
        int col = tile_n + wn + nt * 16 + lr;
        float v = acc[mt][nt][r];
        if (mode == 0) {
          ((unsigned short*)Cv)[(size_t)row * ldc + col] = f2bf(v);
        } else if (mode == 3) {
          ((unsigned short*)Cv)[(size_t)row * ldc + col] = f2bf(v * qscale);
        } else if (mode == 1) {
          int tl = row & 2047;
          int key = tl & 63;
          int tp = (tl & ~63) | ((key & 15) << 2) | (key >> 4);
          ((unsigned short*)Cv)[((size_t)((row >> 11) << 11) + col) * 2048 + tp] = f2bf(v);
        } else {
          ((float*)Cv)[(size_t)row * ldc + col] = v + bias[col];
        }
      }
    }
  }
}

__global__ __launch_bounds__(256)
void gemm_k128(const unsigned short* __restrict__ A, int lda,
               const unsigned short* __restrict__ B, int ldb,
               void* __restrict__ C, int ldc, const float* __restrict__ bias,
               int K, int mode) {
  gemm_body<128>(A, lda, B, ldb, C, ldc, bias, 1.0f, K, mode);
}

__global__ __launch_bounds__(256)
void gemm_k64(const unsigned short* __restrict__ A, int lda,
              const unsigned short* __restrict__ B, int ldb,
              void* __restrict__ C, int ldc, const float* __restrict__ bias,
              int K, int mode) {
  gemm_body<64>(A, lda, B, ldb, C, ldc, bias, 1.0f, K, mode);
}

// batched up-projection: z=0 -> Q (scaled), z=1 -> K, z=2 -> V^T permuted
__global__ __launch_bounds__(256)
void gemm_up(const unsigned short* __restrict__ cdown,
             const unsigned short* __restrict__ wup,
             unsigned short* __restrict__ qb,
             unsigned short* __restrict__ kb,
             unsigned short* __restrict__ vtb) {
  const int z = blockIdx.z;
  const unsigned short* A = cdown + z * 512;
  const unsigned short* B = wup + (size_t)z * 1048576;
  void* C; int mode; float qs = 1.0f;
  if (z == 0)      { C = qb;  mode = 3; qs = 0.12751744f; }  // (1/sqrt(128))*log2(e)
  else if (z == 1) { C = kb;  mode = 0; }
  else             { C = vtb; mode = 1; }
  gemm_body<128>(A, 1536, B, 512, C, 2048, nullptr, qs, 512, mode);
}

// ---------- flash attention (unshifted softmax, log2 domain) ----------
// 512 threads / 8 waves / 128 q-rows per block; 16 q-rows per wave.
__global__ __launch_bounds__(512)
void attn(const unsigned short* __restrict__ q,
          const unsigned short* __restrict__ k,
          const unsigned short* __restrict__ vt,
          unsigned short* __restrict__ o) {
  __shared__ __align__(16) unsigned short Ks[64 * 128];
  __shared__ __align__(16) unsigned short Vs[128 * 64];
  __shared__ __align__(16) unsigned short Ps[8][16 * 64];

  const int tid  = threadIdx.x;
  const int wave = tid >> 6, lane = tid & 63;
  const int lr = lane & 15, lg = lane >> 4;
  const int bh = blockIdx.y;
  const int b = bh >> 4, h = bh & 15;
  const int q0 = blockIdx.x * 128;

  const size_t qrow = (size_t)(b * 2048 + q0 + wave * 16 + lr);
  short8 qf[4];
#pragma unroll
  for (int kk = 0; kk < 4; kk++)
    qf[kk] = *(const short8*)(q + qrow * 2048 + h * 128 + kk * 32 + lg * 8);

  f32x4 oacc[8];
  f32x4 lacc = (f32x4)0.0f;
#pragma unroll
  for (int n2 = 0; n2 < 8; n2++) oacc[n2] = (f32x4)0.0f;

  short8 ones;
#pragma unroll
  for (int j = 0; j < 8; j++) ones[j] = (short)0x3F80;  // bf16 1.0

  const unsigned short* kg = k  + (size_t)(b * 2048 + (tid >> 4)) * 2048 + h * 128
                               + ((((tid & 15) ^ (tid >> 4)) & 15) << 3);
  const unsigned short* vg = vt + (size_t)(bh * 128 + (tid >> 3)) * 2048
                               + (((tid & 7) ^ ((tid >> 3) & 7)) << 3);
  const int lr7 = lr & 7;

  for (int kt = 0; kt < 2048; kt += 64) {
#pragma unroll
    for (int i = 0; i < 2; i++) {
      async16(kg + (size_t)(kt + i * 32) * 2048, Ks + i * 4096 + wave * 512);
      async16(vg + kt + (size_t)(i * 64) * 2048, Vs + i * 4096 + wave * 512);
    }
    __syncthreads();

    // S = Q K^T
    f32x4 sv[4];
#pragma unroll
    for (int nt = 0; nt < 4; nt++) sv[nt] = (f32x4)0.0f;
#pragma unroll
    for (int nt = 0; nt < 4; nt++) {
#pragma unroll
      for (int kk = 0; kk < 4; kk++) {
        short8 kf = *(const short8*)&Ks[(nt * 16 + lr) * 128 + (((kk * 4 + lg) ^ lr) << 3)];
        sv[nt] = mfma16(qf[kk], kf, sv[nt]);
      }
    }

    // p = 2^s; packed bf16 write to Ps in permuted-key layout
#pragma unroll
    for (int r = 0; r < 4; r++) {
      float p0 = exp2r(sv[0][r]);
      float p1 = exp2r(sv[1][r]);
      float p2 = exp2r(sv[2][r]);
      float p3 = exp2r(sv[3][r]);
      uint2 pk; pk.x = pkbf(p0, p1); pk.y = pkbf(p2, p3);
      int row = lg * 4 + r;
      *(uint2*)&Ps[wave][row * 64 + ((lr ^ (lg << 2)) << 2)] = pk;
    }

    // O += P V ; l += P 1
#pragma unroll
    for (int kt2 = 0; kt2 < 2; kt2++) {
      short8 pf = *(const short8*)&Ps[wave]
          [lr * 64 + (((kt2 * 8 + lg * 2) ^ ((lr >> 2) << 2)) << 2)];
      lacc = mfma16(pf, ones, lacc);
#pragma unroll
      for (int n2 = 0; n2 < 8; n2++) {
        short8 vf = *(const short8*)&Vs[(n2 * 16 + lr) * 64 + (((kt2 * 4 + lg) ^ lr7) << 3)];
        oacc[n2] = mfma16(pf, vf, oacc[n2]);
      }
    }
    __syncthreads();
  }

  // epilogue: l in C-layout aligned with oacc rows
  f32x4 inv;
#pragma unroll
  for (int r = 0; r < 4; r++) inv[r] = 1.0f / lacc[r];
#pragma unroll
  for (int n2 = 0; n2 < 8; n2++)
#pragma unroll
    for (int r = 0; r < 4; r++) {
      size_t row = (size_t)(b * 2048 + q0 + wave * 16 + lg * 4 + r);
      o[row * 2048 + h * 128 + n2 * 16 + lr] = f2bf(oacc[n2][r] * inv[r]);
    }
}

// ---------- host ----------
extern "C" void kernel_launch(void* const* d_in, const int* in_sizes, int n_in,
                              void* d_out, int out_size, void* d_ws, size_t ws_size,
                              hipStream_t stream) {
  const float* x    = (const float*)d_in[0];
  const float* wq_a = (const float*)d_in[1];
  const float* wq_b = (const float*)d_in[2];
  const float* wk_a = (const float*)d_in[3];
  const float* wk_b = (const float*)d_in[4];
  const float* wv_a = (const float*)d_in[5];
  const float* wv_b = (const float*)d_in[6];
  const float* wo_w = (const float*)d_in[7];
  const float* wo_b = (const float*)d_in[8];
  float* out = (float*)d_out;

  unsigned short* ws = (unsigned short*)d_ws;
  unsigned short* xb    = ws;
  unsigned short* wdown = ws + 8388608;    // [1536][2048]
  unsigned short* wupb  = ws + 11534336;   // [3][2048][512]
  unsigned short* wow   = ws + 14680064;   // [2048][2048]
  unsigned short* cdown = ws + 18874368;   // [4096][1536]
  unsigned short* qb    = ws + 25165824;   // [4096][2048]
  unsigned short* kb    = ws + 33554432;
  unsigned short* vtb   = ws + 41943040;
  unsigned short* ao    = ws + 50331648;

  cast_all<<<dim3(2048), dim3(256), 0, stream>>>(x, wq_a, wq_b, wk_a, wk_b, wv_a, wv_b, wo_w, ws);

  // fused down-projection: [4096,2048] x [1536,2048]^T -> [4096,1536]
  gemm_k64<<<dim3(24, 32), dim3(256), 0, stream>>>(xb, 2048, wdown, 2048, cdown, 1536, nullptr, 2048, 0);

  // batched up-projections (Q scaled, K plain, V transposed+permuted)
  gemm_up<<<dim3(16, 32, 3), dim3(256), 0, stream>>>(cdown, wupb, qb, kb, vtb);

  attn<<<dim3(16, 32), dim3(512), 0, stream>>>(qb, kb, vtb, ao);

  // output projection + bias -> fp32
  gemm_k128<<<dim3(16, 32), dim3(256), 0, stream>>>(ao, 2048, wow, 2048, out, 2048, wo_b, 2048, 2);
}